// Round 9
// baseline (360.833 us; speedup 1.0000x reference)
//
#include <hip/hip_runtime.h>

#define B_ 256
#define T_ 1024
#define V_ 5000
#define D_ 100
#define H_ 64
#define C_ 2

// ---------------------------------------------------------------------------
// Kernel 1: EW[v][h] = sum_d E[v][d] * W[d][h] + b[h]
// ---------------------------------------------------------------------------
__global__ __launch_bounds__(256) void ew_kernel(const float* __restrict__ E,
                                                 const float* __restrict__ W,
                                                 const float* __restrict__ bias,
                                                 float* __restrict__ EW) {
    int idx = blockIdx.x * 256 + threadIdx.x;   // 0 .. V_*H_
    if (idx >= V_ * H_) return;
    int h = idx & (H_ - 1);
    int v = idx >> 6;
    float acc = bias[h];
    const float* Erow = E + v * D_;
    #pragma unroll 4
    for (int d = 0; d < D_; ++d) {
        acc = fmaf(Erow[d], W[d * H_ + h], acc);
    }
    EW[idx] = acc;
}

// ---------------------------------------------------------------------------
// Kernel 2: per-batch RNN, one wave per batch element.
//
// R4-R8 evidence: any 64x(readlane->fma) chain costs 560-690 cyc/step no
// matter how scheduled; R5 (DS ops interleaved between pairs) was the
// fastest variant. So: broadcast h through the DS pipe instead.
//   - per step: 1 ds_write_b32 of h, then h[0..15] via readlane+fma
//     (covers the write->read latency window), h[16..63] via 12 BROADCAST
//     ds_read_b128 (all lanes same address = conflict-free broadcast)
//     feeding 48 pure-VGPR fmas (no SGPR-write hazard).
//   - single wave => no barriers; in-wave DS ordering makes one h-buffer
//     safe (next step's write queues behind this step's reads).
//   - U stays register-pinned (R7-validated: waves_per_eu(1,1) + launder).
// Failure signature: dur unchanged => broadcast round-trip is structural
// -> pivot to 4-wave split-K (clean exchange) or MFMA.
// ---------------------------------------------------------------------------
__device__ __forceinline__ float readlane_f(float v, int lane) {
    return __uint_as_float(__builtin_amdgcn_readlane(__float_as_uint(v), lane));
}

__global__ __launch_bounds__(64)
__attribute__((amdgpu_waves_per_eu(1, 1)))
void rnn_kernel(const int* __restrict__ tokens,
                const float* __restrict__ EW,
                const float* __restrict__ U,
                const float* __restrict__ Wd,
                const float* __restrict__ bd,
                float* __restrict__ out) {
    const int b = blockIdx.x;     // batch element
    const int j = threadIdx.x;    // 0..63 : hidden unit

    __shared__ int    sh_tok[T_ + 2];   // 4 KB + pad
    __shared__ float4 sh_h4[H_ / 4];    // 256 B: h broadcast buffer
    float* sh_h = (float*)sh_h4;

    const int* tok = tokens + b * T_;
    #pragma unroll
    for (int k = 0; k < T_ / H_; ++k) {
        sh_tok[k * H_ + j] = tok[k * H_ + j];    // coalesced
    }
    if (j < 2) sh_tok[T_ + j] = 0;               // pad: kills tail guard
    __syncthreads();

    // ---- U column j -> 64 VGPRs (R7-validated: VGPR_Count=132) ----
    float u[H_];
    #pragma unroll
    for (int i = 0; i < H_; ++i) {
        float v = U[i * H_ + j];
        asm volatile("" : "+v"(v));   // opaque def: no remat of the load
        u[i] = v;
    }

    float h = 0.f;
    float pooled = 0.f;

    // 2-step-deep xw prefetch pipeline
    int2 tkA = *(const int2*)&sh_tok[0];
    float xw0 = EW[tkA.x * H_ + j];
    float xw1 = EW[tkA.y * H_ + j];

    // one recurrence step: hybrid broadcast (16 readlane + 48 LDS-bcast)
    #define RNN_STEP(tokv, xwv)                                          \
    {                                                                    \
        sh_h[j] = h;                       /* ds_write_b32, 2 lanes/bank */\
        /* part 1: i in [0,16) via readlane -- fills the write latency */ \
        float b0 = 0.f, b1 = 0.f, b2 = 0.f, b3 = 0.f;                    \
        _Pragma("unroll")                                                \
        for (int m = 0; m < 4; ++m) {                                    \
            b0 = fmaf(readlane_f(h, 4 * m + 0), u[4 * m + 0], b0);       \
            b1 = fmaf(readlane_f(h, 4 * m + 1), u[4 * m + 1], b1);       \
            b2 = fmaf(readlane_f(h, 4 * m + 2), u[4 * m + 2], b2);       \
            b3 = fmaf(readlane_f(h, 4 * m + 3), u[4 * m + 3], b3);       \
        }                                                                \
        /* part 2: i in [16,64) via broadcast b128 reads (DS pipe) */    \
        float a0 = 0.f, a1 = 0.f, a2 = 0.f, a3 = 0.f;                    \
        _Pragma("unroll")                                                \
        for (int q = 4; q < 16; ++q) {                                   \
            const float4 hv = sh_h4[q];    /* same addr all lanes */     \
            a0 = fmaf(hv.x, u[4 * q + 0], a0);                           \
            a1 = fmaf(hv.y, u[4 * q + 1], a1);                           \
            a2 = fmaf(hv.z, u[4 * q + 2], a2);                           \
            a3 = fmaf(hv.w, u[4 * q + 3], a3);                           \
        }                                                                \
        float x = (((a0 + b0) + (a1 + b1)) + ((a2 + b2) + (a3 + b3)))    \
                  + (xwv);                                               \
        float e = __expf(2.f * x);                                       \
        float r = __builtin_amdgcn_rcpf(e + 1.f);                        \
        float hn = fmaf(-2.f, r, 1.f);                                   \
        h = ((tokv) != 0) ? hn : h;                                      \
        pooled += h;                                                     \
    }

    for (int t = 0; t < T_; t += 2) {
        // prefetch steps t+2, t+3 (pad makes tail reads safe: EW[0])
        int2 tkB = *(const int2*)&sh_tok[t + 2];
        float xw2 = EW[tkB.x * H_ + j];
        float xw3 = EW[tkB.y * H_ + j];

        RNN_STEP(tkA.x, xw0);
        RNN_STEP(tkA.y, xw1);

        tkA = tkB;
        xw0 = xw2;
        xw1 = xw3;
    }
    #undef RNN_STEP

    // ---- epilogue: pooled mean -> dense(2) -> sigmoid ----
    float p = pooled * (1.0f / (float)T_);
    float v0 = p * Wd[j * C_ + 0];
    float v1 = p * Wd[j * C_ + 1];
    #pragma unroll
    for (int off = 32; off >= 1; off >>= 1) {
        v0 += __shfl_down(v0, off, 64);
        v1 += __shfl_down(v1, off, 64);
    }
    if (j == 0) {
        float l0 = v0 + bd[0];
        float l1 = v1 + bd[1];
        out[b * C_ + 0] = 1.f / (1.f + __expf(-l0));
        out[b * C_ + 1] = 1.f / (1.f + __expf(-l1));
    }
}

// ---------------------------------------------------------------------------
extern "C" void kernel_launch(void* const* d_in, const int* in_sizes, int n_in,
                              void* d_out, int out_size, void* d_ws, size_t ws_size,
                              hipStream_t stream) {
    const int*   tokens = (const int*)  d_in[0];  // [B,T] int32
    const float* E      = (const float*)d_in[1];  // [V,D]
    const float* W      = (const float*)d_in[2];  // [D,H]
    const float* U      = (const float*)d_in[3];  // [H,H]
    const float* bias   = (const float*)d_in[4];  // [H]
    const float* Wd     = (const float*)d_in[5];  // [H,C]
    const float* bd     = (const float*)d_in[6];  // [C]
    float* out = (float*)d_out;                   // [B,C]
    float* EW  = (float*)d_ws;                    // [V,H] scratch: 1.28 MB

    ew_kernel<<<(V_ * H_ + 255) / 256, 256, 0, stream>>>(E, W, bias, EW);
    rnn_kernel<<<B_, H_, 0, stream>>>(tokens, EW, U, Wd, bd, out);
}

// Round 10
// 319.267 us; speedup vs baseline: 1.1302x; 1.1302x over previous
//
#include <hip/hip_runtime.h>

#define B_ 256
#define T_ 1024
#define V_ 5000
#define D_ 100
#define H_ 64
#define C_ 2

typedef float f32x2 __attribute__((ext_vector_type(2)));

// ---------------------------------------------------------------------------
// Kernel 1: EW[v][h] = sum_d E[v][d] * W[d][h] + b[h]
// ---------------------------------------------------------------------------
__global__ __launch_bounds__(256) void ew_kernel(const float* __restrict__ E,
                                                 const float* __restrict__ W,
                                                 const float* __restrict__ bias,
                                                 float* __restrict__ EW) {
    int idx = blockIdx.x * 256 + threadIdx.x;   // 0 .. V_*H_
    if (idx >= V_ * H_) return;
    int h = idx & (H_ - 1);
    int v = idx >> 6;
    float acc = bias[h];
    const float* Erow = E + v * D_;
    #pragma unroll 4
    for (int d = 0; d < D_; ++d) {
        acc = fmaf(Erow[d], W[d * H_ + h], acc);
    }
    EW[idx] = acc;
}

// ---------------------------------------------------------------------------
// Kernel 2: per-batch RNN, one wave per batch element.
//
// R4-R9 model: wall time = 1024 x single-wave step latency; every
// broadcast scheme lands at 560-700 cyc/step, consistent with readlane
// ~4 cyc + fma ~2 cyc issue and R5 already ~76% issue-bound. Levers left:
//  - v_pk_fma_f32 (packed fp32): 2 MACs/inst, fed by an SGPR PAIR formed
//    from two consecutive readlane results -> 64 rl + 32 pk vs 64+64.
//  - ONE asm block for the whole dot: two sgpr banks s[80:83]/s[84:87],
//    software-pipelined RL(c+1) || PK(c); single block so the compiler
//    can never place its own values in the banks between uses.
//  - U column pinned in 32 VGPR pairs (R7-validated launder + waves_per_eu).
// ---------------------------------------------------------------------------

#define RL4(b0,b1,b2,b3,l0,l1,l2,l3) \
    "v_readlane_b32 " b0 ", %[h], " #l0 "\n\t" \
    "v_readlane_b32 " b1 ", %[h], " #l1 "\n\t" \
    "v_readlane_b32 " b2 ", %[h], " #l2 "\n\t" \
    "v_readlane_b32 " b3 ", %[h], " #l3 "\n\t"

#define PK2(pa,pb,aA,aB,uA,uB) \
    "v_pk_fma_f32 %[" aA "], " pa ", %[" uA "], %[" aA "]\n\t" \
    "v_pk_fma_f32 %[" aB "], " pb ", %[" uB "], %[" aB "]\n\t"

__global__ __launch_bounds__(64)
__attribute__((amdgpu_waves_per_eu(1, 1)))
void rnn_kernel(const int* __restrict__ tokens,
                const float* __restrict__ EW,
                const float* __restrict__ U,
                const float* __restrict__ Wd,
                const float* __restrict__ bd,
                float* __restrict__ out) {
    const int b = blockIdx.x;     // batch element
    const int j = threadIdx.x;    // 0..63 : hidden unit

    __shared__ int sh_tok[T_ + 2];   // 4 KB + pad

    const int* tok = tokens + b * T_;
    #pragma unroll
    for (int k = 0; k < T_ / H_; ++k) {
        sh_tok[k * H_ + j] = tok[k * H_ + j];    // coalesced
    }
    if (j < 2) sh_tok[T_ + j] = 0;               // pad: kills tail guard
    __syncthreads();

    // ---- U column j -> 32 VGPR pairs: u2[i] = (U[2i][j], U[2i+1][j]) ----
    f32x2 u2[H_ / 2];
    #pragma unroll
    for (int i = 0; i < H_ / 2; ++i) {
        f32x2 p = { U[(2 * i) * H_ + j], U[(2 * i + 1) * H_ + j] };
        asm volatile("" : "+v"(p));   // opaque def: no remat of the loads
        u2[i] = p;
    }

    float h = 0.f;
    float pooled = 0.f;

    // 2-step-deep xw prefetch pipeline
    int2 tkA = *(const int2*)&sh_tok[0];
    float xw0 = EW[tkA.x * H_ + j];
    float xw1 = EW[tkA.y * H_ + j];

    // one recurrence step: hand-scheduled 64 readlane + 32 pk_fma dot
    #define RNN_STEP(tokv, xwv)                                           \
    {                                                                     \
        f32x2 _a0 = {0.f, 0.f}, _a1 = {0.f, 0.f};                         \
        f32x2 _a2 = {0.f, 0.f}, _a3 = {0.f, 0.f};                         \
        asm volatile(                                                     \
            RL4("s80","s81","s82","s83",  0, 1, 2, 3)                     \
            RL4("s84","s85","s86","s87",  4, 5, 6, 7)                     \
            PK2("s[80:81]","s[82:83]","a0","a1","u0","u1")                \
            RL4("s80","s81","s82","s83",  8, 9,10,11)                     \
            PK2("s[84:85]","s[86:87]","a2","a3","u2","u3")                \
            RL4("s84","s85","s86","s87", 12,13,14,15)                     \
            PK2("s[80:81]","s[82:83]","a0","a1","u4","u5")                \
            RL4("s80","s81","s82","s83", 16,17,18,19)                     \
            PK2("s[84:85]","s[86:87]","a2","a3","u6","u7")                \
            RL4("s84","s85","s86","s87", 20,21,22,23)                     \
            PK2("s[80:81]","s[82:83]","a0","a1","u8","u9")                \
            RL4("s80","s81","s82","s83", 24,25,26,27)                     \
            PK2("s[84:85]","s[86:87]","a2","a3","u10","u11")              \
            RL4("s84","s85","s86","s87", 28,29,30,31)                     \
            PK2("s[80:81]","s[82:83]","a0","a1","u12","u13")              \
            RL4("s80","s81","s82","s83", 32,33,34,35)                     \
            PK2("s[84:85]","s[86:87]","a2","a3","u14","u15")              \
            RL4("s84","s85","s86","s87", 36,37,38,39)                     \
            PK2("s[80:81]","s[82:83]","a0","a1","u16","u17")              \
            RL4("s80","s81","s82","s83", 40,41,42,43)                     \
            PK2("s[84:85]","s[86:87]","a2","a3","u18","u19")              \
            RL4("s84","s85","s86","s87", 44,45,46,47)                     \
            PK2("s[80:81]","s[82:83]","a0","a1","u20","u21")              \
            RL4("s80","s81","s82","s83", 48,49,50,51)                     \
            PK2("s[84:85]","s[86:87]","a2","a3","u22","u23")              \
            RL4("s84","s85","s86","s87", 52,53,54,55)                     \
            PK2("s[80:81]","s[82:83]","a0","a1","u24","u25")              \
            RL4("s80","s81","s82","s83", 56,57,58,59)                     \
            PK2("s[84:85]","s[86:87]","a2","a3","u26","u27")              \
            RL4("s84","s85","s86","s87", 60,61,62,63)                     \
            PK2("s[80:81]","s[82:83]","a0","a1","u28","u29")              \
            PK2("s[84:85]","s[86:87]","a2","a3","u30","u31")              \
            : [a0]"+v"(_a0), [a1]"+v"(_a1), [a2]"+v"(_a2), [a3]"+v"(_a3)  \
            : [h]"v"(h),                                                  \
              [u0]"v"(u2[0]),   [u1]"v"(u2[1]),   [u2]"v"(u2[2]),         \
              [u3]"v"(u2[3]),   [u4]"v"(u2[4]),   [u5]"v"(u2[5]),         \
              [u6]"v"(u2[6]),   [u7]"v"(u2[7]),   [u8]"v"(u2[8]),         \
              [u9]"v"(u2[9]),   [u10]"v"(u2[10]), [u11]"v"(u2[11]),       \
              [u12]"v"(u2[12]), [u13]"v"(u2[13]), [u14]"v"(u2[14]),       \
              [u15]"v"(u2[15]), [u16]"v"(u2[16]), [u17]"v"(u2[17]),       \
              [u18]"v"(u2[18]), [u19]"v"(u2[19]), [u20]"v"(u2[20]),       \
              [u21]"v"(u2[21]), [u22]"v"(u2[22]), [u23]"v"(u2[23]),       \
              [u24]"v"(u2[24]), [u25]"v"(u2[25]), [u26]"v"(u2[26]),       \
              [u27]"v"(u2[27]), [u28]"v"(u2[28]), [u29]"v"(u2[29]),       \
              [u30]"v"(u2[30]), [u31]"v"(u2[31])                          \
            : "s80","s81","s82","s83","s84","s85","s86","s87");           \
        f32x2 _s01 = _a0 + _a1;                                           \
        f32x2 _s23 = _a2 + _a3;                                           \
        f32x2 _st  = _s01 + _s23;                                         \
        float _x = (_st.x + _st.y) + (xwv);                               \
        float _e = __expf(2.f * _x);                                      \
        float _r = __builtin_amdgcn_rcpf(_e + 1.f);                       \
        float _hn = fmaf(-2.f, _r, 1.f);                                  \
        h = ((tokv) != 0) ? _hn : h;                                      \
        pooled += h;                                                      \
    }

    for (int t = 0; t < T_; t += 2) {
        // prefetch steps t+2, t+3 (pad makes tail reads safe: EW[0])
        int2 tkB = *(const int2*)&sh_tok[t + 2];
        float xw2 = EW[tkB.x * H_ + j];
        float xw3 = EW[tkB.y * H_ + j];

        RNN_STEP(tkA.x, xw0);
        RNN_STEP(tkA.y, xw1);

        tkA = tkB;
        xw0 = xw2;
        xw1 = xw3;
    }
    #undef RNN_STEP

    // ---- epilogue: pooled mean -> dense(2) -> sigmoid ----
    float p = pooled * (1.0f / (float)T_);
    float v0 = p * Wd[j * C_ + 0];
    float v1 = p * Wd[j * C_ + 1];
    #pragma unroll
    for (int off = 32; off >= 1; off >>= 1) {
        v0 += __shfl_down(v0, off, 64);
        v1 += __shfl_down(v1, off, 64);
    }
    if (j == 0) {
        float l0 = v0 + bd[0];
        float l1 = v1 + bd[1];
        out[b * C_ + 0] = 1.f / (1.f + __expf(-l0));
        out[b * C_ + 1] = 1.f / (1.f + __expf(-l1));
    }
}

// ---------------------------------------------------------------------------
extern "C" void kernel_launch(void* const* d_in, const int* in_sizes, int n_in,
                              void* d_out, int out_size, void* d_ws, size_t ws_size,
                              hipStream_t stream) {
    const int*   tokens = (const int*)  d_in[0];  // [B,T] int32
    const float* E      = (const float*)d_in[1];  // [V,D]
    const float* W      = (const float*)d_in[2];  // [D,H]
    const float* U      = (const float*)d_in[3];  // [H,H]
    const float* bias   = (const float*)d_in[4];  // [H]
    const float* Wd     = (const float*)d_in[5];  // [H,C]
    const float* bd     = (const float*)d_in[6];  // [C]
    float* out = (float*)d_out;                   // [B,C]
    float* EW  = (float*)d_ws;                    // [V,H] scratch: 1.28 MB

    ew_kernel<<<(V_ * H_ + 255) / 256, 256, 0, stream>>>(E, W, bias, EW);
    rnn_kernel<<<B_, H_, 0, stream>>>(tokens, EW, U, Wd, bd, out);
}